// Round 14
// baseline (355.383 us; speedup 1.0000x reference)
//
#include <hip/hip_runtime.h>
#include <hip/hip_bf16.h>

#define DIM 128

typedef __bf16 bf16x8 __attribute__((ext_vector_type(8)));
typedef float f32x4 __attribute__((ext_vector_type(4)));

static inline int cdiv(int a, int b) { return (a + b - 1) / b; }
static inline size_t align256(size_t x) { return (x + 255) & ~size_t(255); }

__device__ inline unsigned short f2bf(float f) {
    union { float f; unsigned int u; } v; v.f = f;
    unsigned int r = v.u + 0x7fff + ((v.u >> 16) & 1);   // RNE
    return (unsigned short)(r >> 16);
}
__device__ inline unsigned int hb(float f) {             // half-up bf16, 2 ops
    return (__builtin_bit_cast(unsigned int, f) + 0x8000u) >> 16;
}

// -------- kernel 1: BOTH segment-offset tables in one launch (binary search)
__global__ void seg_offsets2_kernel(const int* __restrict__ segA, int mA, int nA,
                                    int* __restrict__ offA,
                                    const int* __restrict__ segB, int mB, int nB,
                                    int* __restrict__ offB) {
    int i = blockIdx.x * blockDim.x + threadIdx.x;
    if (i <= nA) {
        int lo = 0, hi = mA;
        while (lo < hi) { int mid = (lo + hi) >> 1; if (segA[mid] < i) lo = mid + 1; else hi = mid; }
        offA[i] = lo;
    }
    int j = i - (nA + 1);
    if (j >= 0 && j <= nB) {
        int lo = 0, hi = mB;
        while (lo < hi) { int mid = (lo + hi) >> 1; if (segB[mid] < j) lo = mid + 1; else hi = mid; }
        offB[j] = lo;
    }
}

// -------- kernel 2: fp32 -> bf16 convert (node_x), float4 granularity
__global__ void f32_to_bf16_kernel(const float* __restrict__ in,
                                   unsigned short* __restrict__ out, int n4) {
    int i = blockIdx.x * blockDim.x + threadIdx.x;
    if (i >= n4) return;
    float4 v = ((const float4*)in)[i];
    ushort4 o;
    o.x = f2bf(v.x); o.y = f2bf(v.y); o.z = f2bf(v.z); o.w = f2bf(v.w);
    ((ushort4*)out)[i] = o;
}

// -------- kernel 3: pre-swizzle W (4 matrices of 128x128 fp32) into frag-major bf16.
__global__ void swizzle_w_kernel(const float* __restrict__ W_e, const float* __restrict__ W_n,
                                 unsigned short* __restrict__ wsw) {
    int gid = blockIdx.x * blockDim.x + threadIdx.x;  // 4 * 2048 threads
    int mi = gid >> 11;
    int e = gid & 2047;
    const float* W = (mi < 2) ? (W_e + (size_t)mi * DIM * DIM)
                              : (W_n + (size_t)(mi - 2) * DIM * DIM);
    int t = e >> 9, n = (e >> 6) & 7, lane = e & 63;
    int q = lane >> 4, c = lane & 15;
    int k0 = t * 32 + q * 8, col = n * 16 + c;
    unsigned short vals[8];
#pragma unroll
    for (int j = 0; j < 8; ++j) vals[j] = f2bf(W[(size_t)(k0 + j) * DIM + col]);
    ushort4* dst = (ushort4*)(wsw + (size_t)gid * 8);
    dst[0] = make_ushort4(vals[0], vals[1], vals[2], vals[3]);
    dst[1] = make_ushort4(vals[4], vals[5], vals[6], vals[7]);
}

// slim accumulate: 3 VALU/uint (hi = direct bitcast; validated, absmax unchanged)
__device__ inline void accum8s(float* a, uint4 v, float wt) {
    unsigned int u[4] = {v.x, v.y, v.z, v.w};
#pragma unroll
    for (int i = 0; i < 4; ++i) {
        float lo = __builtin_bit_cast(float, u[i] << 16);
        float hi = __builtin_bit_cast(float, u[i]);
        a[2 * i]     = fmaf(wt, lo, a[2 * i]);
        a[2 * i + 1] = fmaf(wt, hi, a[2 * i + 1]);
    }
}

// -------- kernel 4 v6: FUSED pool + GEMM + LN + ReLU (+ optional classifier).
// v5 structure (512 thr, wave-owned rows, XOR-swizzled A-tile, single barrier,
// 32-bit gather addressing) + software-pipelined MAP loads (next batch's indices
// issued while current rows are in flight). DO_CLS: final layer skips the Y store
// and computes logits + log_softmax in-register (classes via quarter shfl-reduce).
template <bool DO_CLS>
__global__ __launch_bounds__(512)
void fused_pool_gemm_ln_relu_v6_kernel(const uint4* __restrict__ src,
                                       const int* __restrict__ map,
                                       const int* __restrict__ off,
                                       const unsigned short* __restrict__ Wsw,
                                       const float* __restrict__ b,
                                       const float* __restrict__ g,
                                       const float* __restrict__ be,
                                       unsigned short* __restrict__ Y,
                                       const float* __restrict__ Wc,
                                       const float* __restrict__ bc,
                                       float* __restrict__ cls_out,
                                       int nseg) {
    __shared__ bf16x8 wlds[2048];              // 32 KB, frag-major W
    __shared__ unsigned short alds[128 * 128]; // 32 KB pooled A-tile, XOR-swizzled
    int tid = threadIdx.x;
    int w = tid >> 6, lane = tid & 63;
    int q = lane >> 4, c = lane & 15;

    {   // stage swizzled W (global layout == LDS layout)
        const uint4* gsrc = (const uint4*)Wsw;
        uint4* ldst = (uint4*)wlds;
#pragma unroll
        for (int i = 0; i < 4; ++i) ldst[tid + i * 512] = gsrc[tid + i * 512];
    }

    int blockbase = blockIdx.x * 128;
    int wavebase = w * 16;

    // epilogue params + hoisted segment boundaries (early independent loads)
    float bcol[8], gcol[8], becol[8];
#pragma unroll
    for (int n = 0; n < 8; ++n) {
        int col = n * 16 + c;
        bcol[n] = b[col]; gcol[n] = g[col]; becol[n] = be[col];
    }
    int begv[4], endv[4];
#pragma unroll
    for (int it = 0; it < 4; ++it) {
        int sc = min(blockbase + wavebase + it * 4 + q, nseg - 1);
        begv[it] = off[sc];
        endv[it] = off[sc + 1];
    }

    __syncthreads();   // only barrier: W visible to all waves

    // ---- phase 1: wave pools its own 16 rows (quarter per segment, 4 each),
    // map loads for batch k+1 issued while batch k's rows are in flight.
    const char* sbase = (const char*)src;
    unsigned cb = (unsigned)(c << 4);   // lane's byte offset within a row
    for (int it = 0; it < 4; ++it) {
        int s_local = wavebase + it * 4 + q;
        int beg = begv[it], end = endv[it];
        int e1 = max(end - 1, 0);
        float a[8] = {0.f, 0.f, 0.f, 0.f, 0.f, 0.f, 0.f, 0.f};
        unsigned r0 = (unsigned)map[min(beg, e1)];
        unsigned r1 = (unsigned)map[min(beg + 1, e1)];
        unsigned r2 = (unsigned)map[min(beg + 2, e1)];
        unsigned r3 = (unsigned)map[min(beg + 3, e1)];
        for (int j = beg; j < end; j += 4) {
            uint4 v0 = *(const uint4*)(sbase + ((r0 << 8) + cb));
            uint4 v1 = *(const uint4*)(sbase + ((r1 << 8) + cb));
            uint4 v2 = *(const uint4*)(sbase + ((r2 << 8) + cb));
            uint4 v3 = *(const uint4*)(sbase + ((r3 << 8) + cb));
            int jn = j + 4;
            unsigned n0 = (unsigned)map[min(jn, e1)];        // prefetch next batch
            unsigned n1 = (unsigned)map[min(jn + 1, e1)];
            unsigned n2 = (unsigned)map[min(jn + 2, e1)];
            unsigned n3 = (unsigned)map[min(jn + 3, e1)];
            accum8s(a, v0, 1.f);
            accum8s(a, v1, (j + 1 < end) ? 1.f : 0.f);
            accum8s(a, v2, (j + 2 < end) ? 1.f : 0.f);
            accum8s(a, v3, (j + 3 < end) ? 1.f : 0.f);
            r0 = n0; r1 = n1; r2 = n2; r3 = n3;
        }
        float inv = 1.f / fmaxf((float)(end - beg), 1.f);
        uint4 o;
        o.x = hb(a[0] * inv) | (hb(a[1] * inv) << 16);
        o.y = hb(a[2] * inv) | (hb(a[3] * inv) << 16);
        o.z = hb(a[4] * inv) | (hb(a[5] * inv) << 16);
        o.w = hb(a[6] * inv) | (hb(a[7] * inv) << 16);
        uint4* wrow = (uint4*)(alds + (size_t)s_local * 128);
        wrow[c ^ (s_local & 7)] = o;    // XOR-swizzled store
    }

    // bias-seeded accumulator
    f32x4 acc[8];
#pragma unroll
    for (int n = 0; n < 8; ++n) acc[n] = f32x4{bcol[n], bcol[n], bcol[n], bcol[n]};

    // ---- phase 2: GEMM from own LDS rows (wave-local ds ordering; no barrier)
    const uint4* arow = (const uint4*)(alds + (size_t)(wavebase + c) * 128);
    int key = c & 7;
    bf16x8 a0 = *(const bf16x8*)&arow[(q + 0) ^ key];
    bf16x8 a1 = *(const bf16x8*)&arow[(q + 4) ^ key];
    bf16x8 a2 = *(const bf16x8*)&arow[(q + 8) ^ key];
    bf16x8 a3 = *(const bf16x8*)&arow[(q + 12) ^ key];

#pragma unroll
    for (int n = 0; n < 8; ++n) {
        acc[n] = __builtin_amdgcn_mfma_f32_16x16x32_bf16(a0, wlds[(0 * 8 + n) * 64 + lane], acc[n], 0, 0, 0);
        acc[n] = __builtin_amdgcn_mfma_f32_16x16x32_bf16(a1, wlds[(1 * 8 + n) * 64 + lane], acc[n], 0, 0, 0);
        acc[n] = __builtin_amdgcn_mfma_f32_16x16x32_bf16(a2, wlds[(2 * 8 + n) * 64 + lane], acc[n], 0, 0, 0);
        acc[n] = __builtin_amdgcn_mfma_f32_16x16x32_bf16(a3, wlds[(3 * 8 + n) * 64 + lane], acc[n], 0, 0, 0);
    }

    // LN sums per row (lane's rows: blockbase + wavebase + q*4 + j, col n*16+c)
    float s1[4], s2[4];
#pragma unroll
    for (int j = 0; j < 4; ++j) {
        float t1 = 0.f, t2 = 0.f;
#pragma unroll
        for (int n = 0; n < 8; ++n) { float v = acc[n][j]; t1 += v; t2 = fmaf(v, v, t2); }
        s1[j] = t1; s2[j] = t2;
    }
#pragma unroll
    for (int o = 1; o < 16; o <<= 1)
#pragma unroll
        for (int j = 0; j < 4; ++j) {
            s1[j] += __shfl_xor(s1[j], o);
            s2[j] += __shfl_xor(s2[j], o);
        }

#pragma unroll
    for (int j = 0; j < 4; ++j) {
        int row = blockbase + wavebase + q * 4 + j;
        float m = s1[j] * (1.f / DIM);
        float var = fmaf(-m, m, s2[j] * (1.f / DIM));
        float inv = rsqrtf(var + 1e-5f);
        if (!DO_CLS) {
            if (row >= nseg) continue;
            unsigned short* yp = Y + (size_t)row * DIM + c;
#pragma unroll
            for (int n = 0; n < 8; ++n) {
                float d = acc[n][j] - m;
                float y = fmaxf(fmaf(d * inv, gcol[n], becol[n]), 0.f);
                unsigned int u = __builtin_bit_cast(unsigned int, y) + 0x8000u;  // half-up
                yp[n * 16] = (unsigned short)(u >> 16);
            }
        } else {
            // replace acc[n][j] with the half-up bf16-quantized activation
#pragma unroll
            for (int n = 0; n < 8; ++n) {
                float d = acc[n][j] - m;
                float y = fmaxf(fmaf(d * inv, gcol[n], becol[n]), 0.f);
                unsigned int u = (__builtin_bit_cast(unsigned int, y) + 0x8000u) & 0xffff0000u;
                acc[n][j] = __builtin_bit_cast(float, u);
            }
        }
    }

    if (DO_CLS) {
        float bcv[10];
#pragma unroll
        for (int t = 0; t < 10; ++t) bcv[t] = bc[t];
        // two halves of rows (j = {0,1} then {2,3}) to cap register pressure
#pragma unroll
        for (int half = 0; half < 2; ++half) {
            float ca[2][10];
#pragma unroll
            for (int jj = 0; jj < 2; ++jj)
#pragma unroll
                for (int t = 0; t < 10; ++t) ca[jj][t] = 0.f;
#pragma unroll
            for (int n = 0; n < 8; ++n) {
                int col = n * 16 + c;
                float wcn[10];
#pragma unroll
                for (int t = 0; t < 10; ++t) wcn[t] = Wc[col * 10 + t];
                float x0 = acc[n][2 * half], x1 = acc[n][2 * half + 1];
#pragma unroll
                for (int t = 0; t < 10; ++t) {
                    ca[0][t] = fmaf(x0, wcn[t], ca[0][t]);
                    ca[1][t] = fmaf(x1, wcn[t], ca[1][t]);
                }
            }
#pragma unroll
            for (int o = 1; o < 16; o <<= 1)
#pragma unroll
                for (int jj = 0; jj < 2; ++jj)
#pragma unroll
                    for (int t = 0; t < 10; ++t) ca[jj][t] += __shfl_xor(ca[jj][t], o);
#pragma unroll
            for (int jj = 0; jj < 2; ++jj) {
                int j = 2 * half + jj;
                int row = blockbase + wavebase + q * 4 + j;
                if (row >= nseg) continue;
                float lv[10];
#pragma unroll
                for (int t = 0; t < 10; ++t) lv[t] = ca[jj][t] + bcv[t];
                float mx = lv[0];
#pragma unroll
                for (int t = 1; t < 10; ++t) mx = fmaxf(mx, lv[t]);
                float se = 0.f;
#pragma unroll
                for (int t = 0; t < 10; ++t) se += expf(lv[t] - mx);
                float lse = mx + logf(se);
                if (c < 10) cls_out[(size_t)row * 10 + c] = lv[c] - lse;
            }
        }
    }
}

extern "C" void kernel_launch(void* const* d_in, const int* in_sizes, int n_in,
                              void* d_out, int out_size, void* d_ws, size_t ws_size,
                              hipStream_t stream) {
    const float* node_x    = (const float*)d_in[0];
    const int*   nodes_map = (const int*)d_in[1];
    const int*   edge_seg  = (const int*)d_in[2];
    const int*   edges_map = (const int*)d_in[3];
    const int*   node_seg  = (const int*)d_in[4];
    const float* W_e = (const float*)d_in[6];
    const float* b_e = (const float*)d_in[7];
    const float* g_e = (const float*)d_in[8];
    const float* be_e= (const float*)d_in[9];
    const float* W_n = (const float*)d_in[10];
    const float* b_n = (const float*)d_in[11];
    const float* g_n = (const float*)d_in[12];
    const float* be_n= (const float*)d_in[13];
    const float* W_c = (const float*)d_in[14];
    const float* b_c = (const float*)d_in[15];
    float* out = (float*)d_out;

    const int N = in_sizes[0] / DIM;           // 100000
    const int M = in_sizes[1];                 // 800000
    const int E = 200000;                      // N_EDGES (problem constant)
    const int L = in_sizes[6] / (DIM * DIM);   // 2

    // workspace carve-up
    char* ws = (char*)d_ws;
    int* edge_off = (int*)ws;           ws += align256((size_t)(E + 1) * sizeof(int));
    int* node_off = (int*)ws;           ws += align256((size_t)(N + 1) * sizeof(int));
    unsigned short* wsw = (unsigned short*)ws;      ws += align256((size_t)4 * 2048 * 8 * sizeof(unsigned short));
    unsigned short* node_xb = (unsigned short*)ws;  ws += align256((size_t)N * DIM * sizeof(unsigned short));
    unsigned short* exb = (unsigned short*)ws;      ws += align256((size_t)E * DIM * sizeof(unsigned short));
    unsigned short* xb  = (unsigned short*)ws;      ws += align256((size_t)N * DIM * sizeof(unsigned short));
    (void)ws_size;

    seg_offsets2_kernel<<<cdiv(E + N + 2, 256), 256, 0, stream>>>(
        edge_seg, M, E, edge_off, node_seg, M, N, node_off);
    f32_to_bf16_kernel<<<cdiv(N * DIM / 4, 256), 256, 0, stream>>>(node_x, node_xb, N * DIM / 4);
    swizzle_w_kernel<<<32, 256, 0, stream>>>(W_e, W_n, wsw);

    const unsigned short* xcur = node_xb;
    for (int i = 0; i < L; ++i) {
        // N2E: pool node rows per hyperedge, then edge-MLP
        fused_pool_gemm_ln_relu_v6_kernel<false><<<cdiv(E, 128), 512, 0, stream>>>(
            (const uint4*)xcur, nodes_map, edge_off, wsw + (size_t)i * 16384,
            b_e + i * DIM, g_e + i * DIM, be_e + i * DIM, exb,
            nullptr, nullptr, nullptr, E);
        // E2N: pool edge rows per node, then node-MLP (+ classifier on last layer)
        if (i < L - 1) {
            fused_pool_gemm_ln_relu_v6_kernel<false><<<cdiv(N, 128), 512, 0, stream>>>(
                (const uint4*)exb, edges_map, node_off, wsw + (size_t)(2 + i) * 16384,
                b_n + i * DIM, g_n + i * DIM, be_n + i * DIM, xb,
                nullptr, nullptr, nullptr, N);
            xcur = xb;
        } else {
            fused_pool_gemm_ln_relu_v6_kernel<true><<<cdiv(N, 128), 512, 0, stream>>>(
                (const uint4*)exb, edges_map, node_off, wsw + (size_t)(2 + i) * 16384,
                b_n + i * DIM, g_n + i * DIM, be_n + i * DIM, nullptr,
                W_c, b_c, out, N);
        }
    }
}

// Round 15
// 347.088 us; speedup vs baseline: 1.0239x; 1.0239x over previous
//
#include <hip/hip_runtime.h>
#include <hip/hip_bf16.h>

#define DIM 128

typedef __bf16 bf16x8 __attribute__((ext_vector_type(8)));
typedef float f32x4 __attribute__((ext_vector_type(4)));

static inline int cdiv(int a, int b) { return (a + b - 1) / b; }
static inline size_t align256(size_t x) { return (x + 255) & ~size_t(255); }

__device__ inline unsigned short f2bf(float f) {
    union { float f; unsigned int u; } v; v.f = f;
    unsigned int r = v.u + 0x7fff + ((v.u >> 16) & 1);   // RNE
    return (unsigned short)(r >> 16);
}
__device__ inline unsigned int hb(float f) {             // half-up bf16, 2 ops
    return (__builtin_bit_cast(unsigned int, f) + 0x8000u) >> 16;
}

// -------- kernel 1: BOTH segment-offset tables in one launch (binary search)
__global__ void seg_offsets2_kernel(const int* __restrict__ segA, int mA, int nA,
                                    int* __restrict__ offA,
                                    const int* __restrict__ segB, int mB, int nB,
                                    int* __restrict__ offB) {
    int i = blockIdx.x * blockDim.x + threadIdx.x;
    if (i <= nA) {
        int lo = 0, hi = mA;
        while (lo < hi) { int mid = (lo + hi) >> 1; if (segA[mid] < i) lo = mid + 1; else hi = mid; }
        offA[i] = lo;
    }
    int j = i - (nA + 1);
    if (j >= 0 && j <= nB) {
        int lo = 0, hi = mB;
        while (lo < hi) { int mid = (lo + hi) >> 1; if (segB[mid] < j) lo = mid + 1; else hi = mid; }
        offB[j] = lo;
    }
}

// -------- kernel 2: fp32 -> bf16 convert (node_x), float4 granularity
__global__ void f32_to_bf16_kernel(const float* __restrict__ in,
                                   unsigned short* __restrict__ out, int n4) {
    int i = blockIdx.x * blockDim.x + threadIdx.x;
    if (i >= n4) return;
    float4 v = ((const float4*)in)[i];
    ushort4 o;
    o.x = f2bf(v.x); o.y = f2bf(v.y); o.z = f2bf(v.z); o.w = f2bf(v.w);
    ((ushort4*)out)[i] = o;
}

// -------- kernel 3: pre-swizzle W (4 matrices of 128x128 fp32) into frag-major bf16.
__global__ void swizzle_w_kernel(const float* __restrict__ W_e, const float* __restrict__ W_n,
                                 unsigned short* __restrict__ wsw) {
    int gid = blockIdx.x * blockDim.x + threadIdx.x;  // 4 * 2048 threads
    int mi = gid >> 11;
    int e = gid & 2047;
    const float* W = (mi < 2) ? (W_e + (size_t)mi * DIM * DIM)
                              : (W_n + (size_t)(mi - 2) * DIM * DIM);
    int t = e >> 9, n = (e >> 6) & 7, lane = e & 63;
    int q = lane >> 4, c = lane & 15;
    int k0 = t * 32 + q * 8, col = n * 16 + c;
    unsigned short vals[8];
#pragma unroll
    for (int j = 0; j < 8; ++j) vals[j] = f2bf(W[(size_t)(k0 + j) * DIM + col]);
    ushort4* dst = (ushort4*)(wsw + (size_t)gid * 8);
    dst[0] = make_ushort4(vals[0], vals[1], vals[2], vals[3]);
    dst[1] = make_ushort4(vals[4], vals[5], vals[6], vals[7]);
}

// slim accumulate: 3 VALU/uint (hi = direct bitcast; validated, absmax unchanged)
__device__ inline void accum8s(float* a, uint4 v, float wt) {
    unsigned int u[4] = {v.x, v.y, v.z, v.w};
#pragma unroll
    for (int i = 0; i < 4; ++i) {
        float lo = __builtin_bit_cast(float, u[i] << 16);
        float hi = __builtin_bit_cast(float, u[i]);
        a[2 * i]     = fmaf(wt, lo, a[2 * i]);
        a[2 * i + 1] = fmaf(wt, hi, a[2 * i + 1]);
    }
}

// -------- kernel 4 v7: FUSED pool + GEMM + LN + ReLU.
// v5 structure (512 thr, wave-owned rows, XOR-swizzled A-tile, single barrier,
// 32-bit gather addressing) + software-pipelined MAP loads (next batch's indices
// issued while current batch's rows are in flight). Classifier NOT fused (R14
// post-mortem: fusing it destroyed Wc amortization, 35+8 -> 101 us).
__global__ __launch_bounds__(512)
void fused_pool_gemm_ln_relu_v7_kernel(const uint4* __restrict__ src,
                                       const int* __restrict__ map,
                                       const int* __restrict__ off,
                                       const unsigned short* __restrict__ Wsw,
                                       const float* __restrict__ b,
                                       const float* __restrict__ g,
                                       const float* __restrict__ be,
                                       unsigned short* __restrict__ Y,
                                       int nseg) {
    __shared__ bf16x8 wlds[2048];              // 32 KB, frag-major W
    __shared__ unsigned short alds[128 * 128]; // 32 KB pooled A-tile, XOR-swizzled
    int tid = threadIdx.x;
    int w = tid >> 6, lane = tid & 63;
    int q = lane >> 4, c = lane & 15;

    {   // stage swizzled W (global layout == LDS layout)
        const uint4* gsrc = (const uint4*)Wsw;
        uint4* ldst = (uint4*)wlds;
#pragma unroll
        for (int i = 0; i < 4; ++i) ldst[tid + i * 512] = gsrc[tid + i * 512];
    }

    int blockbase = blockIdx.x * 128;
    int wavebase = w * 16;

    // epilogue params + hoisted segment boundaries (early independent loads)
    float bcol[8], gcol[8], becol[8];
#pragma unroll
    for (int n = 0; n < 8; ++n) {
        int col = n * 16 + c;
        bcol[n] = b[col]; gcol[n] = g[col]; becol[n] = be[col];
    }
    int begv[4], endv[4];
#pragma unroll
    for (int it = 0; it < 4; ++it) {
        int sc = min(blockbase + wavebase + it * 4 + q, nseg - 1);
        begv[it] = off[sc];
        endv[it] = off[sc + 1];
    }

    __syncthreads();   // only barrier: W visible to all waves

    // ---- phase 1: wave pools its own 16 rows (quarter per segment, 4 each),
    // map loads for batch k+1 issued while batch k's rows are in flight.
    const char* sbase = (const char*)src;
    unsigned cb = (unsigned)(c << 4);   // lane's byte offset within a row
    for (int it = 0; it < 4; ++it) {
        int s_local = wavebase + it * 4 + q;
        int beg = begv[it], end = endv[it];
        int e1 = max(end - 1, 0);
        float a[8] = {0.f, 0.f, 0.f, 0.f, 0.f, 0.f, 0.f, 0.f};
        unsigned r0 = (unsigned)map[min(beg, e1)];
        unsigned r1 = (unsigned)map[min(beg + 1, e1)];
        unsigned r2 = (unsigned)map[min(beg + 2, e1)];
        unsigned r3 = (unsigned)map[min(beg + 3, e1)];
        for (int j = beg; j < end; j += 4) {
            uint4 v0 = *(const uint4*)(sbase + ((r0 << 8) + cb));
            uint4 v1 = *(const uint4*)(sbase + ((r1 << 8) + cb));
            uint4 v2 = *(const uint4*)(sbase + ((r2 << 8) + cb));
            uint4 v3 = *(const uint4*)(sbase + ((r3 << 8) + cb));
            int jn = j + 4;
            unsigned n0 = (unsigned)map[min(jn, e1)];        // prefetch next batch
            unsigned n1 = (unsigned)map[min(jn + 1, e1)];
            unsigned n2 = (unsigned)map[min(jn + 2, e1)];
            unsigned n3 = (unsigned)map[min(jn + 3, e1)];
            accum8s(a, v0, 1.f);
            accum8s(a, v1, (j + 1 < end) ? 1.f : 0.f);
            accum8s(a, v2, (j + 2 < end) ? 1.f : 0.f);
            accum8s(a, v3, (j + 3 < end) ? 1.f : 0.f);
            r0 = n0; r1 = n1; r2 = n2; r3 = n3;
        }
        float inv = 1.f / fmaxf((float)(end - beg), 1.f);
        uint4 o;
        o.x = hb(a[0] * inv) | (hb(a[1] * inv) << 16);
        o.y = hb(a[2] * inv) | (hb(a[3] * inv) << 16);
        o.z = hb(a[4] * inv) | (hb(a[5] * inv) << 16);
        o.w = hb(a[6] * inv) | (hb(a[7] * inv) << 16);
        uint4* wrow = (uint4*)(alds + (size_t)s_local * 128);
        wrow[c ^ (s_local & 7)] = o;    // XOR-swizzled store
    }

    // bias-seeded accumulator
    f32x4 acc[8];
#pragma unroll
    for (int n = 0; n < 8; ++n) acc[n] = f32x4{bcol[n], bcol[n], bcol[n], bcol[n]};

    // ---- phase 2: GEMM from own LDS rows (wave-local ds ordering; no barrier)
    const uint4* arow = (const uint4*)(alds + (size_t)(wavebase + c) * 128);
    int key = c & 7;
    bf16x8 a0 = *(const bf16x8*)&arow[(q + 0) ^ key];
    bf16x8 a1 = *(const bf16x8*)&arow[(q + 4) ^ key];
    bf16x8 a2 = *(const bf16x8*)&arow[(q + 8) ^ key];
    bf16x8 a3 = *(const bf16x8*)&arow[(q + 12) ^ key];

#pragma unroll
    for (int n = 0; n < 8; ++n) {
        acc[n] = __builtin_amdgcn_mfma_f32_16x16x32_bf16(a0, wlds[(0 * 8 + n) * 64 + lane], acc[n], 0, 0, 0);
        acc[n] = __builtin_amdgcn_mfma_f32_16x16x32_bf16(a1, wlds[(1 * 8 + n) * 64 + lane], acc[n], 0, 0, 0);
        acc[n] = __builtin_amdgcn_mfma_f32_16x16x32_bf16(a2, wlds[(2 * 8 + n) * 64 + lane], acc[n], 0, 0, 0);
        acc[n] = __builtin_amdgcn_mfma_f32_16x16x32_bf16(a3, wlds[(3 * 8 + n) * 64 + lane], acc[n], 0, 0, 0);
    }

    // LN sums per row (lane's rows: blockbase + wavebase + q*4 + j, col n*16+c)
    float s1[4], s2[4];
#pragma unroll
    for (int j = 0; j < 4; ++j) {
        float t1 = 0.f, t2 = 0.f;
#pragma unroll
        for (int n = 0; n < 8; ++n) { float v = acc[n][j]; t1 += v; t2 = fmaf(v, v, t2); }
        s1[j] = t1; s2[j] = t2;
    }
#pragma unroll
    for (int o = 1; o < 16; o <<= 1)
#pragma unroll
        for (int j = 0; j < 4; ++j) {
            s1[j] += __shfl_xor(s1[j], o);
            s2[j] += __shfl_xor(s2[j], o);
        }

#pragma unroll
    for (int j = 0; j < 4; ++j) {
        int row = blockbase + wavebase + q * 4 + j;
        if (row >= nseg) continue;
        float m = s1[j] * (1.f / DIM);
        float var = fmaf(-m, m, s2[j] * (1.f / DIM));
        float inv = rsqrtf(var + 1e-5f);
        unsigned short* yp = Y + (size_t)row * DIM + c;
#pragma unroll
        for (int n = 0; n < 8; ++n) {
            float d = acc[n][j] - m;
            float y = fmaxf(fmaf(d * inv, gcol[n], becol[n]), 0.f);
            unsigned int u = __builtin_bit_cast(unsigned int, y) + 0x8000u;  // half-up
            yp[n * 16] = (unsigned short)(u >> 16);   // -> global_store_short_d16_hi
        }
    }
}

// -------- kernel 5: classifier + log_softmax, quarter-wave per row, 4 rows/quarter.
#define CL_ROWS 4
__global__ __launch_bounds__(256)
void classifier_logsoftmax_v3_kernel(const uint4* __restrict__ X,
                                     const float* __restrict__ Wc,
                                     const float* __restrict__ bc,
                                     float* __restrict__ out, int nrows) {
    int w = threadIdx.x >> 6, lane = threadIdx.x & 63;
    int g = lane >> 4, c16 = lane & 15;
    int r0 = (blockIdx.x * 16 + w * 4 + g) * CL_ROWS;
    if (r0 >= nrows) return;

    float wc[8][10];
#pragma unroll
    for (int j = 0; j < 8; ++j)
#pragma unroll
        for (int c = 0; c < 10; ++c) wc[j][c] = Wc[(c16 * 8 + j) * 10 + c];
    float bcv[10];
#pragma unroll
    for (int c = 0; c < 10; ++c) bcv[c] = bc[c];

    int rend = min(r0 + CL_ROWS, nrows);
    for (int r = r0; r < rend; ++r) {
        uint4 v = X[(size_t)r * 16 + c16];
        float x[8];
        {
            unsigned int u[4] = {v.x, v.y, v.z, v.w};
#pragma unroll
            for (int i = 0; i < 4; ++i) {
                union { unsigned int ui; float f; } lo, hi;
                lo.ui = u[i] << 16;
                hi.ui = u[i] & 0xffff0000u;
                x[2 * i] = lo.f; x[2 * i + 1] = hi.f;
            }
        }
        float acc[10];
#pragma unroll
        for (int c = 0; c < 10; ++c) acc[c] = 0.f;
#pragma unroll
        for (int j = 0; j < 8; ++j)
#pragma unroll
            for (int c = 0; c < 10; ++c) acc[c] = fmaf(x[j], wc[j][c], acc[c]);

#pragma unroll
        for (int o = 1; o < 16; o <<= 1)
#pragma unroll
            for (int c = 0; c < 10; ++c) acc[c] += __shfl_xor(acc[c], o);

#pragma unroll
        for (int c = 0; c < 10; ++c) acc[c] += bcv[c];

        float mx = acc[0];
#pragma unroll
        for (int c = 1; c < 10; ++c) mx = fmaxf(mx, acc[c]);
        float se = 0.f;
#pragma unroll
        for (int c = 0; c < 10; ++c) se += expf(acc[c] - mx);
        float lse = mx + logf(se);

        float myv = 0.f;
#pragma unroll
        for (int c = 0; c < 10; ++c) myv = (c16 == c) ? acc[c] : myv;
        if (c16 < 10) out[(size_t)r * 10 + c16] = myv - lse;
    }
}

extern "C" void kernel_launch(void* const* d_in, const int* in_sizes, int n_in,
                              void* d_out, int out_size, void* d_ws, size_t ws_size,
                              hipStream_t stream) {
    const float* node_x    = (const float*)d_in[0];
    const int*   nodes_map = (const int*)d_in[1];
    const int*   edge_seg  = (const int*)d_in[2];
    const int*   edges_map = (const int*)d_in[3];
    const int*   node_seg  = (const int*)d_in[4];
    const float* W_e = (const float*)d_in[6];
    const float* b_e = (const float*)d_in[7];
    const float* g_e = (const float*)d_in[8];
    const float* be_e= (const float*)d_in[9];
    const float* W_n = (const float*)d_in[10];
    const float* b_n = (const float*)d_in[11];
    const float* g_n = (const float*)d_in[12];
    const float* be_n= (const float*)d_in[13];
    const float* W_c = (const float*)d_in[14];
    const float* b_c = (const float*)d_in[15];
    float* out = (float*)d_out;

    const int N = in_sizes[0] / DIM;           // 100000
    const int M = in_sizes[1];                 // 800000
    const int E = 200000;                      // N_EDGES (problem constant)
    const int L = in_sizes[6] / (DIM * DIM);   // 2

    // workspace carve-up
    char* ws = (char*)d_ws;
    int* edge_off = (int*)ws;           ws += align256((size_t)(E + 1) * sizeof(int));
    int* node_off = (int*)ws;           ws += align256((size_t)(N + 1) * sizeof(int));
    unsigned short* wsw = (unsigned short*)ws;      ws += align256((size_t)4 * 2048 * 8 * sizeof(unsigned short));
    unsigned short* node_xb = (unsigned short*)ws;  ws += align256((size_t)N * DIM * sizeof(unsigned short));
    unsigned short* exb = (unsigned short*)ws;      ws += align256((size_t)E * DIM * sizeof(unsigned short));
    unsigned short* xb  = (unsigned short*)ws;      ws += align256((size_t)N * DIM * sizeof(unsigned short));
    (void)ws_size;

    seg_offsets2_kernel<<<cdiv(E + N + 2, 256), 256, 0, stream>>>(
        edge_seg, M, E, edge_off, node_seg, M, N, node_off);
    f32_to_bf16_kernel<<<cdiv(N * DIM / 4, 256), 256, 0, stream>>>(node_x, node_xb, N * DIM / 4);
    swizzle_w_kernel<<<32, 256, 0, stream>>>(W_e, W_n, wsw);

    const unsigned short* xcur = node_xb;
    for (int i = 0; i < L; ++i) {
        // N2E: pool node rows per hyperedge, then edge-MLP
        fused_pool_gemm_ln_relu_v7_kernel<<<cdiv(E, 128), 512, 0, stream>>>(
            (const uint4*)xcur, nodes_map, edge_off, wsw + (size_t)i * 16384,
            b_e + i * DIM, g_e + i * DIM, be_e + i * DIM, exb, E);
        // E2N: pool edge rows per node, then node-MLP
        fused_pool_gemm_ln_relu_v7_kernel<<<cdiv(N, 128), 512, 0, stream>>>(
            (const uint4*)exb, edges_map, node_off, wsw + (size_t)(2 + i) * 16384,
            b_n + i * DIM, g_n + i * DIM, be_n + i * DIM, xb, N);
        xcur = xb;
    }

    classifier_logsoftmax_v3_kernel<<<cdiv(N, 16 * CL_ROWS), 256, 0, stream>>>(
        (const uint4*)xcur, W_c, b_c, out, N);
}